// Round 9
// baseline (493.093 us; speedup 1.0000x reference)
//
#include <hip/hip_runtime.h>
#include <math.h>

#define MD   512
#define NH   8
#define DH   64
#define SEQ  4096
#define NSPLIT 4
#define KEYS_PER_SPLIT (SEQ / NSPLIT)   // 1024

typedef _Float16 f16x8 __attribute__((ext_vector_type(8)));
typedef _Float16 f16x4 __attribute__((ext_vector_type(4)));
typedef float    f32x4 __attribute__((ext_vector_type(4)));

#define LDSTR 72   // f16 row stride: 144 B, 16B-aligned, 2-way bank aliasing max

// ---------------------------------------------------------------- projection GEMM x3 (z-indexed)
// out = in @ W; A fp32 split hi/lo in staging (2-term), W fp32 transposed in staging (hi only).
// z=0: q->Qh (row-major f16), z=1: k->Kh (row-major f16), z=2: v->VTh (transposed [MD][SEQ] f16)
__global__ __launch_bounds__(256)
void proj3(const float* __restrict__ q, const float* __restrict__ k,
           const float* __restrict__ v,
           const float* __restrict__ wq, const float* __restrict__ wk,
           const float* __restrict__ wv,
           _Float16* __restrict__ Qh, _Float16* __restrict__ Kh,
           _Float16* __restrict__ VTh)
{
    const int z = blockIdx.z;
    const float* A32 = (z == 0) ? q : (z == 1) ? k : v;
    const float* W32 = (z == 0) ? wq : (z == 1) ? wk : wv;

    __shared__ _Float16 Ash[64 * LDSTR], Asl[64 * LDSTR], Wsh[64 * LDSTR];

    const int tid  = threadIdx.x;
    const int ln   = tid & 15;
    const int quad = (tid & 63) >> 4;
    const int wv_  = tid >> 6;
    const int wr   = wv_ * 16;
    const int m0   = blockIdx.x * 64;
    const int n0   = blockIdx.y * 64;
    const int srow = tid >> 2;          // 0..63
    const int scol = (tid & 3) << 4;    // 0,16,32,48

    f32x4 acc[4] = {{0.f,0.f,0.f,0.f},{0.f,0.f,0.f,0.f},
                    {0.f,0.f,0.f,0.f},{0.f,0.f,0.f,0.f}};

    for (int k0 = 0; k0 < MD; k0 += 64) {
        const size_t ga = (size_t)(m0 + srow) * MD + k0 + scol;
        const size_t gw = (size_t)(k0 + srow) * MD + n0 + scol;
        float a[16], w[16];
#pragma unroll
        for (int j = 0; j < 4; ++j) {
            const float4 xa = *(const float4*)&A32[ga + j * 4];
            a[j*4+0] = xa.x; a[j*4+1] = xa.y; a[j*4+2] = xa.z; a[j*4+3] = xa.w;
            const float4 xw = *(const float4*)&W32[gw + j * 4];
            w[j*4+0] = xw.x; w[j*4+1] = xw.y; w[j*4+2] = xw.z; w[j*4+3] = xw.w;
        }
        f16x8 ah[2], al[2];
#pragma unroll
        for (int half = 0; half < 2; ++half)
#pragma unroll
            for (int j = 0; j < 8; ++j) {
                const float x = a[half * 8 + j];
                const _Float16 xh = (_Float16)x;
                ah[half][j] = xh;
                al[half][j] = (_Float16)(x - (float)xh);
            }
        __syncthreads();
        *(f16x8*)&Ash[srow * LDSTR + scol]     = ah[0];
        *(f16x8*)&Ash[srow * LDSTR + scol + 8] = ah[1];
        *(f16x8*)&Asl[srow * LDSTR + scol]     = al[0];
        *(f16x8*)&Asl[srow * LDSTR + scol + 8] = al[1];
#pragma unroll
        for (int j = 0; j < 16; ++j)
            Wsh[(scol + j) * LDSTR + srow] = (_Float16)w[j];   // transpose scatter
        __syncthreads();

#pragma unroll
        for (int ks = 0; ks < 2; ++ks) {
            const f16x8 fa = *(f16x8*)&Ash[(wr + ln) * LDSTR + ks * 32 + quad * 8];
            const f16x8 fl = *(f16x8*)&Asl[(wr + ln) * LDSTR + ks * 32 + quad * 8];
#pragma unroll
            for (int nt = 0; nt < 4; ++nt) {
                const f16x8 fb = *(f16x8*)&Wsh[(nt * 16 + ln) * LDSTR + ks * 32 + quad * 8];
                acc[nt] = __builtin_amdgcn_mfma_f32_16x16x32_f16(fa, fb, acc[nt], 0, 0, 0);
                acc[nt] = __builtin_amdgcn_mfma_f32_16x16x32_f16(fl, fb, acc[nt], 0, 0, 0);
            }
        }
    }

    if (z == 2) {   // V: write transposed [MD][SEQ]
#pragma unroll
        for (int nt = 0; nt < 4; ++nt)
#pragma unroll
            for (int r = 0; r < 4; ++r)
                VTh[(size_t)(n0 + nt * 16 + ln) * SEQ + m0 + wr + quad * 4 + r] =
                    (_Float16)acc[nt][r];
    } else {
        _Float16* O = (z == 0) ? Qh : Kh;
#pragma unroll
        for (int nt = 0; nt < 4; ++nt)
#pragma unroll
            for (int r = 0; r < 4; ++r)
                O[(size_t)(m0 + wr + quad * 4 + r) * MD + n0 + nt * 16 + ln] =
                    (_Float16)acc[nt][r];
    }
}

// ---------------------------------------------------------------- MFMA flash attention
// 256 threads = 4 waves x 32 Q-rows = 128-row block; blockIdx.z = key split (4).
// Pure fp16 QK + PV (1 term each); no-max softmax.
// NO min-waves cap: R7 spilled at (256,2)+big shape, R8 starved at (256,4) VGPR=64.
// Natural allocation (~120 VGPR) + 36.9 KB LDS -> 3-4 blocks/CU with full MLP.
__global__ __launch_bounds__(256)
void attn_mfma(const _Float16* __restrict__ Qh_g, const _Float16* __restrict__ Kh_g,
               const _Float16* __restrict__ VTh_g, const float* __restrict__ mask,
               _Float16* __restrict__ Opart, float* __restrict__ lpart)
{
    __shared__ _Float16 Kh[64 * LDSTR];    // [key][d]
    __shared__ _Float16 Vh[64 * LDSTR];    // [d][key]
    __shared__ _Float16 Ph[128 * LDSTR];   // [row][key], wave-private rows

    const int tid  = threadIdx.x;
    const int ln   = tid & 15;
    const int quad = (tid & 63) >> 4;
    const int wv   = tid >> 6;           // 0..3
    const int wr   = wv * 32;            // wave row base (0,32,64,96)
    const int h    = blockIdx.y;
    const int m0   = blockIdx.x * 128;
    const int sp   = blockIdx.z;
    const int tbase = sp * KEYS_PER_SPLIT;

    const int srow = tid >> 2;           // 0..63
    const int scol = (tid & 3) << 4;     // 0,16,32,48

    // Q fragments: 2 rowsets x 2 k-chunks (hi only)
    f16x8 qf[2][2];
#pragma unroll
    for (int rs = 0; rs < 2; ++rs)
#pragma unroll
        for (int ks = 0; ks < 2; ++ks)
            qf[rs][ks] = *(const f16x8*)&Qh_g[(size_t)(m0 + wr + rs * 16 + ln) * MD +
                                              h * DH + ks * 32 + quad * 8];

    f32x4 O[2][4];
#pragma unroll
    for (int rs = 0; rs < 2; ++rs)
#pragma unroll
        for (int d = 0; d < 4; ++d)
            O[rs][d] = (f32x4){0.f, 0.f, 0.f, 0.f};
    float lsum[2][4] = {{0.f,0.f,0.f,0.f},{0.f,0.f,0.f,0.f}};

    const float kSc = 0.125f * 1.4426950408889634f;
    const float kMk = -1e9f * 1.4426950408889634f;

    for (int t = 0; t < KEYS_PER_SPLIT; t += 64) {
        const int t0 = tbase + t;
        const size_t gk = (size_t)(t0 + srow) * MD + h * DH + scol;
        const size_t gv = (size_t)(h * DH + srow) * SEQ + t0 + scol;
        const f16x8 k0 = *(const f16x8*)&Kh_g[gk];
        const f16x8 k1 = *(const f16x8*)&Kh_g[gk + 8];
        const f16x8 v0 = *(const f16x8*)&VTh_g[gv];
        const f16x8 v1 = *(const f16x8*)&VTh_g[gv + 8];
        __syncthreads();
        *(f16x8*)&Kh[srow * LDSTR + scol]     = k0;
        *(f16x8*)&Kh[srow * LDSTR + scol + 8] = k1;
        *(f16x8*)&Vh[srow * LDSTR + scol]     = v0;
        *(f16x8*)&Vh[srow * LDSTR + scol + 8] = v1;
        __syncthreads();

        // S = Q @ K^T (1 term), B-frags shared across both rowsets
        f32x4 s[2][4];
#pragma unroll
        for (int rs = 0; rs < 2; ++rs)
#pragma unroll
            for (int st = 0; st < 4; ++st)
                s[rs][st] = (f32x4){0.f, 0.f, 0.f, 0.f};
#pragma unroll
        for (int st = 0; st < 4; ++st)
#pragma unroll
            for (int ks = 0; ks < 2; ++ks) {
                const f16x8 bh = *(f16x8*)&Kh[(st * 16 + ln) * LDSTR + ks * 32 + quad * 8];
#pragma unroll
                for (int rs = 0; rs < 2; ++rs)
                    s[rs][st] = __builtin_amdgcn_mfma_f32_16x16x32_f16(qf[rs][ks], bh,
                                                                       s[rs][st], 0, 0, 0);
            }

        // softmax numerator (fixed m=0), P -> LDS
#pragma unroll
        for (int rs = 0; rs < 2; ++rs)
#pragma unroll
            for (int st = 0; st < 4; ++st)
#pragma unroll
                for (int r = 0; r < 4; ++r) {
                    const int row = wr + rs * 16 + quad * 4 + r;
                    const float mk = mask[(size_t)(m0 + row) * SEQ + t0 + st * 16 + ln];
                    const float e = exp2f(fmaf(mk, kMk, s[rs][st][r] * kSc));
                    lsum[rs][r] += e;
                    Ph[row * LDSTR + st * 16 + ln] = (_Float16)e;
                }

        // O += P @ V (1 term); wave-private P rows, no barrier
        f16x8 pa[2][2];
#pragma unroll
        for (int rs = 0; rs < 2; ++rs)
#pragma unroll
            for (int ks = 0; ks < 2; ++ks)
                pa[rs][ks] = *(f16x8*)&Ph[(wr + rs * 16 + ln) * LDSTR + ks * 32 + quad * 8];
#pragma unroll
        for (int dst = 0; dst < 4; ++dst)
#pragma unroll
            for (int ks = 0; ks < 2; ++ks) {
                const f16x8 bh = *(f16x8*)&Vh[(dst * 16 + ln) * LDSTR + ks * 32 + quad * 8];
#pragma unroll
                for (int rs = 0; rs < 2; ++rs)
                    O[rs][dst] = __builtin_amdgcn_mfma_f32_16x16x32_f16(pa[rs][ks], bh,
                                                                        O[rs][dst], 0, 0, 0);
            }
    }

    // l reduction across the 16 lanes sharing each row
#pragma unroll
    for (int rs = 0; rs < 2; ++rs)
#pragma unroll
        for (int r = 0; r < 4; ++r)
#pragma unroll
            for (int off = 8; off >= 1; off >>= 1)
                lsum[rs][r] += __shfl_xor(lsum[rs][r], off);

    // epilogue: store UNNORMALIZED partial O (fp16) + partial l
    _Float16* Op = Opart + (size_t)sp * SEQ * MD;
    float*    lp = lpart + ((size_t)sp * NH + h) * SEQ;
#pragma unroll
    for (int rs = 0; rs < 2; ++rs)
#pragma unroll
        for (int r = 0; r < 4; ++r) {
            const int row = m0 + wr + rs * 16 + quad * 4 + r;
            if (ln == 0) lp[row] = lsum[rs][r];
#pragma unroll
            for (int dst = 0; dst < 4; ++dst)
                Op[(size_t)row * MD + h * DH + dst * 16 + ln] = (_Float16)O[rs][dst][r];
        }
}

// ---------------------------------------------------------------- output GEMM with fused split-combine
// out = (sum_sp Opart / sum_sp l) @ Wo + bo.  Ctx materialized per A-tile in staging.
__global__ __launch_bounds__(256)
void gemm_out(const _Float16* __restrict__ Opart, const float* __restrict__ lpart,
              const float* __restrict__ Wo, const float* __restrict__ bo,
              float* __restrict__ out)
{
    const size_t NE = (size_t)SEQ * MD;
    __shared__ _Float16 Ash[64 * LDSTR], Asl[64 * LDSTR], Wsh[64 * LDSTR];

    const int tid  = threadIdx.x;
    const int ln   = tid & 15;
    const int quad = (tid & 63) >> 4;
    const int wv_  = tid >> 6;
    const int wr   = wv_ * 16;
    const int m0   = blockIdx.x * 64;
    const int n0   = blockIdx.y * 64;
    const int srow = tid >> 2;
    const int scol = (tid & 3) << 4;

    f32x4 acc[4] = {{0.f,0.f,0.f,0.f},{0.f,0.f,0.f,0.f},
                    {0.f,0.f,0.f,0.f},{0.f,0.f,0.f,0.f}};

    for (int k0 = 0; k0 < MD; k0 += 64) {
        const int row = m0 + srow;
        const int h   = (k0 + scol) >> 6;
        float l = 0.f;
#pragma unroll
        for (int sp = 0; sp < NSPLIT; ++sp)
            l += lpart[((size_t)sp * NH + h) * SEQ + row];
        const float inv = 1.0f / l;

        float cx[16] = {0.f};
#pragma unroll
        for (int sp = 0; sp < NSPLIT; ++sp) {
            const size_t go = (size_t)sp * NE + (size_t)row * MD + k0 + scol;
            const f16x8 o0 = *(const f16x8*)&Opart[go];
            const f16x8 o1 = *(const f16x8*)&Opart[go + 8];
#pragma unroll
            for (int j = 0; j < 8; ++j) { cx[j] += (float)o0[j]; cx[8 + j] += (float)o1[j]; }
        }
        const size_t gw = (size_t)(k0 + srow) * MD + n0 + scol;
        float w[16];
#pragma unroll
        for (int j = 0; j < 4; ++j) {
            const float4 xw = *(const float4*)&Wo[gw + j * 4];
            w[j*4+0] = xw.x; w[j*4+1] = xw.y; w[j*4+2] = xw.z; w[j*4+3] = xw.w;
        }
        f16x8 ah[2], al[2];
#pragma unroll
        for (int half = 0; half < 2; ++half)
#pragma unroll
            for (int j = 0; j < 8; ++j) {
                const float x = cx[half * 8 + j] * inv;
                const _Float16 xh = (_Float16)x;
                ah[half][j] = xh;
                al[half][j] = (_Float16)(x - (float)xh);
            }
        __syncthreads();
        *(f16x8*)&Ash[srow * LDSTR + scol]     = ah[0];
        *(f16x8*)&Ash[srow * LDSTR + scol + 8] = ah[1];
        *(f16x8*)&Asl[srow * LDSTR + scol]     = al[0];
        *(f16x8*)&Asl[srow * LDSTR + scol + 8] = al[1];
#pragma unroll
        for (int j = 0; j < 16; ++j)
            Wsh[(scol + j) * LDSTR + srow] = (_Float16)w[j];
        __syncthreads();

#pragma unroll
        for (int ks = 0; ks < 2; ++ks) {
            const f16x8 fa = *(f16x8*)&Ash[(wr + ln) * LDSTR + ks * 32 + quad * 8];
            const f16x8 fl = *(f16x8*)&Asl[(wr + ln) * LDSTR + ks * 32 + quad * 8];
#pragma unroll
            for (int nt = 0; nt < 4; ++nt) {
                const f16x8 fb = *(f16x8*)&Wsh[(nt * 16 + ln) * LDSTR + ks * 32 + quad * 8];
                acc[nt] = __builtin_amdgcn_mfma_f32_16x16x32_f16(fa, fb, acc[nt], 0, 0, 0);
                acc[nt] = __builtin_amdgcn_mfma_f32_16x16x32_f16(fl, fb, acc[nt], 0, 0, 0);
            }
        }
    }

#pragma unroll
    for (int nt = 0; nt < 4; ++nt) {
        const float bb = bo[n0 + nt * 16 + ln];
#pragma unroll
        for (int r = 0; r < 4; ++r)
            out[(size_t)(m0 + wr + quad * 4 + r) * MD + n0 + nt * 16 + ln] =
                acc[nt][r] + bb;
    }
}

// ---------------------------------------------------------------- launch
extern "C" void kernel_launch(void* const* d_in, const int* in_sizes, int n_in,
                              void* d_out, int out_size, void* d_ws, size_t ws_size,
                              hipStream_t stream)
{
    const float* q    = (const float*)d_in[0];
    const float* k    = (const float*)d_in[1];
    const float* v    = (const float*)d_in[2];
    const float* mask = (const float*)d_in[3];
    const float* wq   = (const float*)d_in[4];
    const float* wk   = (const float*)d_in[5];
    const float* wv   = (const float*)d_in[6];
    const float* wo   = (const float*)d_in[7];
    const float* bo   = (const float*)d_in[8];
    float* out = (float*)d_out;

    const size_t NE = (size_t)SEQ * MD;   // 2M elements
    _Float16* base = (_Float16*)d_ws;
    _Float16* Qh    = base;               // NE
    _Float16* Kh    = base + NE;          // NE
    _Float16* VTh   = base + 2 * NE;      // NE ([MD][SEQ])
    _Float16* Opart = base + 3 * NE;      // NSPLIT*NE fp16
    float*    lpart = (float*)(base + (3 + NSPLIT) * NE);  // NSPLIT*NH*SEQ fp32

    // 1. q/k/v projections (one dispatch; weight transpose + input split fused)
    proj3<<<dim3(SEQ / 64, MD / 64, 3), 256, 0, stream>>>(q, k, v, wq, wk, wv,
                                                          Qh, Kh, VTh);

    // 2. attention, split-K=4 over keys
    attn_mfma<<<dim3(SEQ / 128, NH, NSPLIT), 256, 0, stream>>>(Qh, Kh, VTh, mask,
                                                               Opart, lpart);

    // 3. output projection (combine + bias fused)
    gemm_out<<<dim3(SEQ / 64, MD / 64), 256, 0, stream>>>(Opart, lpart, wo, bo, out);
}

// Round 10
// 287.934 us; speedup vs baseline: 1.7125x; 1.7125x over previous
//
#include <hip/hip_runtime.h>
#include <math.h>

#define MD   512
#define NH   8
#define DH   64
#define SEQ  4096
#define NSPLIT 2
#define KEYS_PER_SPLIT (SEQ / NSPLIT)   // 2048

typedef _Float16 f16x8 __attribute__((ext_vector_type(8)));
typedef _Float16 f16x4 __attribute__((ext_vector_type(4)));
typedef float    f32x4 __attribute__((ext_vector_type(4)));

#define LDSTR 72   // f16 row stride: 144 B, 16B-aligned, 2-way bank aliasing max

// ---------------------------------------------------------------- projection GEMM x3 (z-indexed)
// out = in @ W; A fp32 split hi/lo in staging (2-term), W transposed in staging (hi only).
// Outputs hi/lo pairs (R6 attention needs them for 3-term QK / 2-term PV ILP):
// z=0: q -> Qh/Ql row-major; z=1: k -> Kh/Kl row-major; z=2: v -> VTh/VTl transposed [MD][SEQ]
__global__ __launch_bounds__(256)
void proj3(const float* __restrict__ q, const float* __restrict__ k,
           const float* __restrict__ v,
           const float* __restrict__ wq, const float* __restrict__ wk,
           const float* __restrict__ wv,
           _Float16* __restrict__ Qh, _Float16* __restrict__ Ql,
           _Float16* __restrict__ Kh, _Float16* __restrict__ Kl,
           _Float16* __restrict__ VTh, _Float16* __restrict__ VTl)
{
    const int z = blockIdx.z;
    const float* A32 = (z == 0) ? q : (z == 1) ? k : v;
    const float* W32 = (z == 0) ? wq : (z == 1) ? wk : wv;

    __shared__ _Float16 Ash[64 * LDSTR], Asl[64 * LDSTR], Wsh[64 * LDSTR];

    const int tid  = threadIdx.x;
    const int ln   = tid & 15;
    const int quad = (tid & 63) >> 4;
    const int wv_  = tid >> 6;
    const int wr   = wv_ * 16;
    const int m0   = blockIdx.x * 64;
    const int n0   = blockIdx.y * 64;
    const int srow = tid >> 2;          // 0..63
    const int scol = (tid & 3) << 4;    // 0,16,32,48

    f32x4 acc[4] = {{0.f,0.f,0.f,0.f},{0.f,0.f,0.f,0.f},
                    {0.f,0.f,0.f,0.f},{0.f,0.f,0.f,0.f}};

    for (int k0 = 0; k0 < MD; k0 += 64) {
        const size_t ga = (size_t)(m0 + srow) * MD + k0 + scol;
        const size_t gw = (size_t)(k0 + srow) * MD + n0 + scol;
        float a[16], w[16];
#pragma unroll
        for (int j = 0; j < 4; ++j) {
            const float4 xa = *(const float4*)&A32[ga + j * 4];
            a[j*4+0] = xa.x; a[j*4+1] = xa.y; a[j*4+2] = xa.z; a[j*4+3] = xa.w;
            const float4 xw = *(const float4*)&W32[gw + j * 4];
            w[j*4+0] = xw.x; w[j*4+1] = xw.y; w[j*4+2] = xw.z; w[j*4+3] = xw.w;
        }
        f16x8 ah[2], al[2];
#pragma unroll
        for (int half = 0; half < 2; ++half)
#pragma unroll
            for (int j = 0; j < 8; ++j) {
                const float x = a[half * 8 + j];
                const _Float16 xh = (_Float16)x;
                ah[half][j] = xh;
                al[half][j] = (_Float16)(x - (float)xh);
            }
        __syncthreads();
        *(f16x8*)&Ash[srow * LDSTR + scol]     = ah[0];
        *(f16x8*)&Ash[srow * LDSTR + scol + 8] = ah[1];
        *(f16x8*)&Asl[srow * LDSTR + scol]     = al[0];
        *(f16x8*)&Asl[srow * LDSTR + scol + 8] = al[1];
#pragma unroll
        for (int j = 0; j < 16; ++j)
            Wsh[(scol + j) * LDSTR + srow] = (_Float16)w[j];   // transpose scatter
        __syncthreads();

#pragma unroll
        for (int ks = 0; ks < 2; ++ks) {
            const f16x8 fa = *(f16x8*)&Ash[(wr + ln) * LDSTR + ks * 32 + quad * 8];
            const f16x8 fl = *(f16x8*)&Asl[(wr + ln) * LDSTR + ks * 32 + quad * 8];
#pragma unroll
            for (int nt = 0; nt < 4; ++nt) {
                const f16x8 fb = *(f16x8*)&Wsh[(nt * 16 + ln) * LDSTR + ks * 32 + quad * 8];
                acc[nt] = __builtin_amdgcn_mfma_f32_16x16x32_f16(fa, fb, acc[nt], 0, 0, 0);
                acc[nt] = __builtin_amdgcn_mfma_f32_16x16x32_f16(fl, fb, acc[nt], 0, 0, 0);
            }
        }
    }

    if (z == 2) {   // V: write hi/lo transposed [MD][SEQ]
#pragma unroll
        for (int nt = 0; nt < 4; ++nt)
#pragma unroll
            for (int r = 0; r < 4; ++r) {
                const float x = acc[nt][r];
                const _Float16 xh = (_Float16)x;
                const size_t idx = (size_t)(n0 + nt * 16 + ln) * SEQ + m0 + wr + quad * 4 + r;
                VTh[idx] = xh;
                VTl[idx] = (_Float16)(x - (float)xh);
            }
    } else {
        _Float16* Oh = (z == 0) ? Qh : Kh;
        _Float16* Ol = (z == 0) ? Ql : Kl;
#pragma unroll
        for (int nt = 0; nt < 4; ++nt)
#pragma unroll
            for (int r = 0; r < 4; ++r) {
                const float x = acc[nt][r];
                const _Float16 xh = (_Float16)x;
                const size_t idx = (size_t)(m0 + wr + quad * 4 + r) * MD + n0 + nt * 16 + ln;
                Oh[idx] = xh;
                Ol[idx] = (_Float16)(x - (float)xh);
            }
    }
}

// ---------------------------------------------------------------- MFMA flash attention (R6 artifact)
// 256 threads = 4 waves x 32 Q-rows = 128-row block; blockIdx.z = key split (2).
// hi/lo staged K/V, 3-term QK, 2-term PV, no-max softmax. Measured 148.5 us @R6;
// the "redundant" lo-terms double as latency hiders (R7-R9 lesson: 1-term starves ILP).
__global__ __launch_bounds__(256)
void attn_mfma(const _Float16* __restrict__ Qhi, const _Float16* __restrict__ Qlo,
               const _Float16* __restrict__ Khi_g, const _Float16* __restrict__ Klo_g,
               const _Float16* __restrict__ VThi_g, const _Float16* __restrict__ VTlo_g,
               const float* __restrict__ mask,
               _Float16* __restrict__ Opart, float* __restrict__ lpart)
{
    __shared__ _Float16 Kh[64 * LDSTR], Kl[64 * LDSTR];   // [key][d]
    __shared__ _Float16 Vh[64 * LDSTR], Vl[64 * LDSTR];   // [d][key]
    __shared__ _Float16 Ph[128 * LDSTR];                  // [row][key], wave-private rows

    const int tid  = threadIdx.x;
    const int ln   = tid & 15;
    const int quad = (tid & 63) >> 4;
    const int wv   = tid >> 6;           // 0..3
    const int wr   = wv * 32;            // wave row base (0,32,64,96)
    const int h    = blockIdx.y;
    const int m0   = blockIdx.x * 128;
    const int sp   = blockIdx.z;
    const int tbase = sp * KEYS_PER_SPLIT;

    const int srow = tid >> 2;           // 0..63
    const int scol = (tid & 3) << 4;     // 0,16,32,48

    // Q fragments: 2 rowsets x 2 k-chunks, hi/lo
    f16x8 qh[2][2], ql[2][2];
#pragma unroll
    for (int rs = 0; rs < 2; ++rs)
#pragma unroll
        for (int ks = 0; ks < 2; ++ks) {
            const size_t off = (size_t)(m0 + wr + rs * 16 + ln) * MD + h * DH + ks * 32 + quad * 8;
            qh[rs][ks] = *(const f16x8*)&Qhi[off];
            ql[rs][ks] = *(const f16x8*)&Qlo[off];
        }

    f32x4 O[2][4];
#pragma unroll
    for (int rs = 0; rs < 2; ++rs)
#pragma unroll
        for (int d = 0; d < 4; ++d)
            O[rs][d] = (f32x4){0.f, 0.f, 0.f, 0.f};
    float lsum[2][4] = {{0.f,0.f,0.f,0.f},{0.f,0.f,0.f,0.f}};

    const float kSc = 0.125f * 1.4426950408889634f;
    const float kMk = -1e9f * 1.4426950408889634f;

    for (int t = 0; t < KEYS_PER_SPLIT; t += 64) {
        const int t0 = tbase + t;
        // stage K [key][d] hi/lo, V^T [d][key] hi/lo: 2 f16x8 per buffer per thread
        const size_t gk = (size_t)(t0 + srow) * MD + h * DH + scol;
        const size_t gv = (size_t)(h * DH + srow) * SEQ + t0 + scol;
        const f16x8 kh0 = *(const f16x8*)&Khi_g[gk];
        const f16x8 kh1 = *(const f16x8*)&Khi_g[gk + 8];
        const f16x8 kl0 = *(const f16x8*)&Klo_g[gk];
        const f16x8 kl1 = *(const f16x8*)&Klo_g[gk + 8];
        const f16x8 vh0 = *(const f16x8*)&VThi_g[gv];
        const f16x8 vh1 = *(const f16x8*)&VThi_g[gv + 8];
        const f16x8 vl0 = *(const f16x8*)&VTlo_g[gv];
        const f16x8 vl1 = *(const f16x8*)&VTlo_g[gv + 8];
        __syncthreads();
        *(f16x8*)&Kh[srow * LDSTR + scol]     = kh0;
        *(f16x8*)&Kh[srow * LDSTR + scol + 8] = kh1;
        *(f16x8*)&Kl[srow * LDSTR + scol]     = kl0;
        *(f16x8*)&Kl[srow * LDSTR + scol + 8] = kl1;
        *(f16x8*)&Vh[srow * LDSTR + scol]     = vh0;
        *(f16x8*)&Vh[srow * LDSTR + scol + 8] = vh1;
        *(f16x8*)&Vl[srow * LDSTR + scol]     = vl0;
        *(f16x8*)&Vl[srow * LDSTR + scol + 8] = vl1;
        __syncthreads();

        // S = Q @ K^T (3-term split), B-frags shared across both rowsets
        f32x4 s[2][4];
#pragma unroll
        for (int rs = 0; rs < 2; ++rs)
#pragma unroll
            for (int st = 0; st < 4; ++st)
                s[rs][st] = (f32x4){0.f, 0.f, 0.f, 0.f};
#pragma unroll
        for (int st = 0; st < 4; ++st)
#pragma unroll
            for (int ks = 0; ks < 2; ++ks) {
                const f16x8 bh = *(f16x8*)&Kh[(st * 16 + ln) * LDSTR + ks * 32 + quad * 8];
                const f16x8 bl = *(f16x8*)&Kl[(st * 16 + ln) * LDSTR + ks * 32 + quad * 8];
#pragma unroll
                for (int rs = 0; rs < 2; ++rs) {
                    s[rs][st] = __builtin_amdgcn_mfma_f32_16x16x32_f16(qh[rs][ks], bh, s[rs][st], 0, 0, 0);
                    s[rs][st] = __builtin_amdgcn_mfma_f32_16x16x32_f16(qh[rs][ks], bl, s[rs][st], 0, 0, 0);
                    s[rs][st] = __builtin_amdgcn_mfma_f32_16x16x32_f16(ql[rs][ks], bh, s[rs][st], 0, 0, 0);
                }
            }

        // softmax numerator (fixed m=0), P -> LDS (hi only)
#pragma unroll
        for (int rs = 0; rs < 2; ++rs)
#pragma unroll
            for (int st = 0; st < 4; ++st)
#pragma unroll
                for (int r = 0; r < 4; ++r) {
                    const int row = wr + rs * 16 + quad * 4 + r;
                    const float mk = mask[(size_t)(m0 + row) * SEQ + t0 + st * 16 + ln];
                    const float e = exp2f(fmaf(mk, kMk, s[rs][st][r] * kSc));
                    lsum[rs][r] += e;
                    Ph[row * LDSTR + st * 16 + ln] = (_Float16)e;
                }

        // O += P @ V (2-term: Ph x (Vh + Vl)); wave-private P rows, no barrier
        f16x8 pa[2][2];
#pragma unroll
        for (int rs = 0; rs < 2; ++rs)
#pragma unroll
            for (int ks = 0; ks < 2; ++ks)
                pa[rs][ks] = *(f16x8*)&Ph[(wr + rs * 16 + ln) * LDSTR + ks * 32 + quad * 8];
#pragma unroll
        for (int dst = 0; dst < 4; ++dst)
#pragma unroll
            for (int ks = 0; ks < 2; ++ks) {
                const f16x8 bh = *(f16x8*)&Vh[(dst * 16 + ln) * LDSTR + ks * 32 + quad * 8];
                const f16x8 bl = *(f16x8*)&Vl[(dst * 16 + ln) * LDSTR + ks * 32 + quad * 8];
#pragma unroll
                for (int rs = 0; rs < 2; ++rs) {
                    O[rs][dst] = __builtin_amdgcn_mfma_f32_16x16x32_f16(pa[rs][ks], bh, O[rs][dst], 0, 0, 0);
                    O[rs][dst] = __builtin_amdgcn_mfma_f32_16x16x32_f16(pa[rs][ks], bl, O[rs][dst], 0, 0, 0);
                }
            }
    }

    // l reduction across the 16 lanes sharing each row
#pragma unroll
    for (int rs = 0; rs < 2; ++rs)
#pragma unroll
        for (int r = 0; r < 4; ++r)
#pragma unroll
            for (int off = 8; off >= 1; off >>= 1)
                lsum[rs][r] += __shfl_xor(lsum[rs][r], off);

    // epilogue: store UNNORMALIZED partial O (fp16, |O|<=l*max|V| well under 65504) + partial l
    _Float16* Op = Opart + (size_t)sp * SEQ * MD;
    float*    lp = lpart + ((size_t)sp * NH + h) * SEQ;
#pragma unroll
    for (int rs = 0; rs < 2; ++rs)
#pragma unroll
        for (int r = 0; r < 4; ++r) {
            const int row = m0 + wr + rs * 16 + quad * 4 + r;
            if (ln == 0) lp[row] = lsum[rs][r];
#pragma unroll
            for (int dst = 0; dst < 4; ++dst)
                Op[(size_t)row * MD + h * DH + dst * 16 + ln] = (_Float16)O[rs][dst][r];
        }
}

// ---------------------------------------------------------------- output GEMM with fused split-combine
// out = (sum_sp Opart / sum_sp l) @ Wo + bo.  Ctx materialized per A-tile in staging.
__global__ __launch_bounds__(256)
void gemm_out(const _Float16* __restrict__ Opart, const float* __restrict__ lpart,
              const float* __restrict__ Wo, const float* __restrict__ bo,
              float* __restrict__ out)
{
    const size_t NE = (size_t)SEQ * MD;
    __shared__ _Float16 Ash[64 * LDSTR], Asl[64 * LDSTR], Wsh[64 * LDSTR];

    const int tid  = threadIdx.x;
    const int ln   = tid & 15;
    const int quad = (tid & 63) >> 4;
    const int wv_  = tid >> 6;
    const int wr   = wv_ * 16;
    const int m0   = blockIdx.x * 64;
    const int n0   = blockIdx.y * 64;
    const int srow = tid >> 2;
    const int scol = (tid & 3) << 4;

    f32x4 acc[4] = {{0.f,0.f,0.f,0.f},{0.f,0.f,0.f,0.f},
                    {0.f,0.f,0.f,0.f},{0.f,0.f,0.f,0.f}};

    for (int k0 = 0; k0 < MD; k0 += 64) {
        const int row = m0 + srow;
        const int h   = (k0 + scol) >> 6;
        float l = 0.f;
#pragma unroll
        for (int sp = 0; sp < NSPLIT; ++sp)
            l += lpart[((size_t)sp * NH + h) * SEQ + row];
        const float inv = 1.0f / l;

        float cx[16] = {0.f};
#pragma unroll
        for (int sp = 0; sp < NSPLIT; ++sp) {
            const size_t go = (size_t)sp * NE + (size_t)row * MD + k0 + scol;
            const f16x8 o0 = *(const f16x8*)&Opart[go];
            const f16x8 o1 = *(const f16x8*)&Opart[go + 8];
#pragma unroll
            for (int j = 0; j < 8; ++j) { cx[j] += (float)o0[j]; cx[8 + j] += (float)o1[j]; }
        }
        const size_t gw = (size_t)(k0 + srow) * MD + n0 + scol;
        float w[16];
#pragma unroll
        for (int j = 0; j < 4; ++j) {
            const float4 xw = *(const float4*)&Wo[gw + j * 4];
            w[j*4+0] = xw.x; w[j*4+1] = xw.y; w[j*4+2] = xw.z; w[j*4+3] = xw.w;
        }
        f16x8 ah[2], al[2];
#pragma unroll
        for (int half = 0; half < 2; ++half)
#pragma unroll
            for (int j = 0; j < 8; ++j) {
                const float x = cx[half * 8 + j] * inv;
                const _Float16 xh = (_Float16)x;
                ah[half][j] = xh;
                al[half][j] = (_Float16)(x - (float)xh);
            }
        __syncthreads();
        *(f16x8*)&Ash[srow * LDSTR + scol]     = ah[0];
        *(f16x8*)&Ash[srow * LDSTR + scol + 8] = ah[1];
        *(f16x8*)&Asl[srow * LDSTR + scol]     = al[0];
        *(f16x8*)&Asl[srow * LDSTR + scol + 8] = al[1];
#pragma unroll
        for (int j = 0; j < 16; ++j)
            Wsh[(scol + j) * LDSTR + srow] = (_Float16)w[j];
        __syncthreads();

#pragma unroll
        for (int ks = 0; ks < 2; ++ks) {
            const f16x8 fa = *(f16x8*)&Ash[(wr + ln) * LDSTR + ks * 32 + quad * 8];
            const f16x8 fl = *(f16x8*)&Asl[(wr + ln) * LDSTR + ks * 32 + quad * 8];
#pragma unroll
            for (int nt = 0; nt < 4; ++nt) {
                const f16x8 fb = *(f16x8*)&Wsh[(nt * 16 + ln) * LDSTR + ks * 32 + quad * 8];
                acc[nt] = __builtin_amdgcn_mfma_f32_16x16x32_f16(fa, fb, acc[nt], 0, 0, 0);
                acc[nt] = __builtin_amdgcn_mfma_f32_16x16x32_f16(fl, fb, acc[nt], 0, 0, 0);
            }
        }
    }

#pragma unroll
    for (int nt = 0; nt < 4; ++nt) {
        const float bb = bo[n0 + nt * 16 + ln];
#pragma unroll
        for (int r = 0; r < 4; ++r)
            out[(size_t)(m0 + wr + quad * 4 + r) * MD + n0 + nt * 16 + ln] =
                acc[nt][r] + bb;
    }
}

// ---------------------------------------------------------------- launch
extern "C" void kernel_launch(void* const* d_in, const int* in_sizes, int n_in,
                              void* d_out, int out_size, void* d_ws, size_t ws_size,
                              hipStream_t stream)
{
    const float* q    = (const float*)d_in[0];
    const float* k    = (const float*)d_in[1];
    const float* v    = (const float*)d_in[2];
    const float* mask = (const float*)d_in[3];
    const float* wq   = (const float*)d_in[4];
    const float* wk   = (const float*)d_in[5];
    const float* wv   = (const float*)d_in[6];
    const float* wo   = (const float*)d_in[7];
    const float* bo   = (const float*)d_in[8];
    float* out = (float*)d_out;

    const size_t NE = (size_t)SEQ * MD;   // 2M elements
    _Float16* base = (_Float16*)d_ws;
    _Float16* Qh    = base;               // NE each
    _Float16* Ql    = base + NE;
    _Float16* Kh    = base + 2 * NE;
    _Float16* Kl    = base + 3 * NE;
    _Float16* VTh   = base + 4 * NE;      // [MD][SEQ]
    _Float16* VTl   = base + 5 * NE;
    _Float16* Opart = base + 6 * NE;      // NSPLIT*NE fp16
    float*    lpart = (float*)(base + (6 + NSPLIT) * NE);  // NSPLIT*NH*SEQ fp32

    // 1. q/k/v projections (one dispatch; weight transpose + input split fused, hi/lo out)
    proj3<<<dim3(SEQ / 64, MD / 64, 3), 256, 0, stream>>>(q, k, v, wq, wk, wv,
                                                          Qh, Ql, Kh, Kl, VTh, VTl);

    // 2. attention, split-K=2 over keys (R6 config)
    attn_mfma<<<dim3(SEQ / 128, NH, NSPLIT), 256, 0, stream>>>(Qh, Ql, Kh, Kl, VTh, VTl,
                                                               mask, Opart, lpart);

    // 3. output projection (combine + bias fused)
    gemm_out<<<dim3(SEQ / 64, MD / 64), 256, 0, stream>>>(Opart, lpart, wo, bo, out);
}

// Round 11
// 260.893 us; speedup vs baseline: 1.8900x; 1.1036x over previous
//
#include <hip/hip_runtime.h>
#include <math.h>

#define MD   512
#define NH   8
#define DH   64
#define SEQ  4096
#define NSPLIT 2
#define KEYS_PER_SPLIT (SEQ / NSPLIT)   // 2048

typedef _Float16 f16x8 __attribute__((ext_vector_type(8)));
typedef _Float16 f16x4 __attribute__((ext_vector_type(4)));
typedef float    f32x4 __attribute__((ext_vector_type(4)));

#define LDSTR 72   // f16 row stride: 144 B, 16B-aligned, 2-way bank aliasing max
#define KMK   (-1.0e9f * 1.4426950408889634f)   // mask -> exp2-domain bias
#define KSC   (0.125f * 1.4426950408889634f)    // 1/sqrt(64) * log2(e)

// ---------------------------------------------------------------- proj3m: q/k/v projections + mask permute
// z=0: q -> Qh/Ql; z=1: k -> Kh (hi only; 2-term QK carries lo on Q side);
// z=2: v -> VTh transposed [MD][SEQ] (hi only; 1-term PV);
// z=3: mask -> maskP f16 exp2-domain, permuted to attention's (rs,st,r) fragment order:
//      maskP[((bx*64+tg)*4 + c)*2048 + tid*8 + j], c=rs*2+(st>>1), j=(st&1)*4+r
__global__ __launch_bounds__(256)
void proj3m(const float* __restrict__ q, const float* __restrict__ k,
            const float* __restrict__ v, const float* __restrict__ mask,
            const float* __restrict__ wq, const float* __restrict__ wk,
            const float* __restrict__ wv,
            _Float16* __restrict__ Qh, _Float16* __restrict__ Ql,
            _Float16* __restrict__ Kh, _Float16* __restrict__ VTh,
            _Float16* __restrict__ maskP)
{
    const int z   = blockIdx.z;
    const int tid = threadIdx.x;

    if (z == 3) {   // ---- mask permute+convert: 512 blocks x 4 (bx,tg) pairs
        const int wv_  = tid >> 6;
        const int quad = (tid & 63) >> 4;
        const int ln   = tid & 15;
#pragma unroll
        for (int i = 0; i < 4; ++i) {
            const int idx = ((blockIdx.y * 64 + blockIdx.x) << 2) + i;   // 0..2047
            const int bx = idx >> 6;     // 128-row tile
            const int tg = idx & 63;     // 64-key tile
            _Float16* outp = maskP + (size_t)idx * 8192;
#pragma unroll
            for (int c = 0; c < 4; ++c) {
                f16x8 hv;
#pragma unroll
                for (int j = 0; j < 8; ++j) {
                    const int rs = c >> 1;
                    const int st = ((c & 1) << 1) + (j >> 2);
                    const int r  = j & 3;
                    const int row = bx * 128 + wv_ * 32 + rs * 16 + quad * 4 + r;
                    const int col = tg * 64 + st * 16 + ln;
                    hv[j] = (_Float16)(mask[(size_t)row * SEQ + col] * KMK);
                }
                *(f16x8*)&outp[((size_t)c * 256 + tid) * 8] = hv;
            }
        }
        return;
    }

    const float* A32 = (z == 0) ? q : (z == 1) ? k : v;
    const float* W32 = (z == 0) ? wq : (z == 1) ? wk : wv;

    __shared__ _Float16 Ash[64 * LDSTR], Asl[64 * LDSTR], Wsh[64 * LDSTR];

    const int ln   = tid & 15;
    const int quad = (tid & 63) >> 4;
    const int wv_  = tid >> 6;
    const int wr   = wv_ * 16;
    const int m0   = blockIdx.x * 64;
    const int n0   = blockIdx.y * 64;
    const int srow = tid >> 2;          // 0..63
    const int scol = (tid & 3) << 4;    // 0,16,32,48

    f32x4 acc[4] = {{0.f,0.f,0.f,0.f},{0.f,0.f,0.f,0.f},
                    {0.f,0.f,0.f,0.f},{0.f,0.f,0.f,0.f}};

    for (int k0 = 0; k0 < MD; k0 += 64) {
        const size_t ga = (size_t)(m0 + srow) * MD + k0 + scol;
        const size_t gw = (size_t)(k0 + srow) * MD + n0 + scol;
        float a[16], w[16];
#pragma unroll
        for (int j = 0; j < 4; ++j) {
            const float4 xa = *(const float4*)&A32[ga + j * 4];
            a[j*4+0] = xa.x; a[j*4+1] = xa.y; a[j*4+2] = xa.z; a[j*4+3] = xa.w;
            const float4 xw = *(const float4*)&W32[gw + j * 4];
            w[j*4+0] = xw.x; w[j*4+1] = xw.y; w[j*4+2] = xw.z; w[j*4+3] = xw.w;
        }
        f16x8 ah[2], al[2];
#pragma unroll
        for (int half = 0; half < 2; ++half)
#pragma unroll
            for (int j = 0; j < 8; ++j) {
                const float x = a[half * 8 + j];
                const _Float16 xh = (_Float16)x;
                ah[half][j] = xh;
                al[half][j] = (_Float16)(x - (float)xh);
            }
        __syncthreads();
        *(f16x8*)&Ash[srow * LDSTR + scol]     = ah[0];
        *(f16x8*)&Ash[srow * LDSTR + scol + 8] = ah[1];
        *(f16x8*)&Asl[srow * LDSTR + scol]     = al[0];
        *(f16x8*)&Asl[srow * LDSTR + scol + 8] = al[1];
#pragma unroll
        for (int j = 0; j < 16; ++j)
            Wsh[(scol + j) * LDSTR + srow] = (_Float16)w[j];   // transpose scatter
        __syncthreads();

#pragma unroll
        for (int ks = 0; ks < 2; ++ks) {
            const f16x8 fa = *(f16x8*)&Ash[(wr + ln) * LDSTR + ks * 32 + quad * 8];
            const f16x8 fl = *(f16x8*)&Asl[(wr + ln) * LDSTR + ks * 32 + quad * 8];
#pragma unroll
            for (int nt = 0; nt < 4; ++nt) {
                const f16x8 fb = *(f16x8*)&Wsh[(nt * 16 + ln) * LDSTR + ks * 32 + quad * 8];
                acc[nt] = __builtin_amdgcn_mfma_f32_16x16x32_f16(fa, fb, acc[nt], 0, 0, 0);
                acc[nt] = __builtin_amdgcn_mfma_f32_16x16x32_f16(fl, fb, acc[nt], 0, 0, 0);
            }
        }
    }

    if (z == 2) {   // V hi, transposed [MD][SEQ]
#pragma unroll
        for (int nt = 0; nt < 4; ++nt)
#pragma unroll
            for (int r = 0; r < 4; ++r)
                VTh[(size_t)(n0 + nt * 16 + ln) * SEQ + m0 + wr + quad * 4 + r] =
                    (_Float16)acc[nt][r];
    } else if (z == 1) {   // K hi only
#pragma unroll
        for (int nt = 0; nt < 4; ++nt)
#pragma unroll
            for (int r = 0; r < 4; ++r)
                Kh[(size_t)(m0 + wr + quad * 4 + r) * MD + n0 + nt * 16 + ln] =
                    (_Float16)acc[nt][r];
    } else {               // Q hi/lo
#pragma unroll
        for (int nt = 0; nt < 4; ++nt)
#pragma unroll
            for (int r = 0; r < 4; ++r) {
                const float x = acc[nt][r];
                const _Float16 xh = (_Float16)x;
                const size_t idx = (size_t)(m0 + wr + quad * 4 + r) * MD + n0 + nt * 16 + ln;
                Qh[idx] = xh;
                Ql[idx] = (_Float16)(x - (float)xh);
            }
    }
}

// ---------------------------------------------------------------- MFMA flash attention
// 256 threads = 4 waves x 32 Q-rows = 128-row block; blockIdx.z = key split (2).
// 2-term QK (Qh,Ql x Kh), 1-term PV (P x Vh), no-max softmax, permuted f16 mask bias.
// LDS 36.9 KB -> 4 blocks/CU (16 waves); mask = 4 coalesced f16x8 loads/tile.
__global__ __launch_bounds__(256)
void attn_mfma(const _Float16* __restrict__ Qhi, const _Float16* __restrict__ Qlo,
               const _Float16* __restrict__ Kh_g, const _Float16* __restrict__ VTh_g,
               const _Float16* __restrict__ maskP,
               _Float16* __restrict__ Opart, float* __restrict__ lpart)
{
    __shared__ _Float16 Kh[64 * LDSTR];    // [key][d]
    __shared__ _Float16 Vh[64 * LDSTR];    // [d][key]
    __shared__ _Float16 Ph[128 * LDSTR];   // [row][key], wave-private rows

    const int tid  = threadIdx.x;
    const int ln   = tid & 15;
    const int quad = (tid & 63) >> 4;
    const int wv   = tid >> 6;           // 0..3
    const int wr   = wv * 32;            // wave row base
    const int h    = blockIdx.y;
    const int m0   = blockIdx.x * 128;
    const int sp   = blockIdx.z;
    const int tbase = sp * KEYS_PER_SPLIT;

    const int srow = tid >> 2;           // 0..63
    const int scol = (tid & 3) << 4;     // 0,16,32,48

    // Q fragments: 2 rowsets x 2 k-chunks, hi/lo
    f16x8 qh[2][2], ql[2][2];
#pragma unroll
    for (int rs = 0; rs < 2; ++rs)
#pragma unroll
        for (int ks = 0; ks < 2; ++ks) {
            const size_t off = (size_t)(m0 + wr + rs * 16 + ln) * MD + h * DH + ks * 32 + quad * 8;
            qh[rs][ks] = *(const f16x8*)&Qhi[off];
            ql[rs][ks] = *(const f16x8*)&Qlo[off];
        }

    f32x4 O[2][4];
#pragma unroll
    for (int rs = 0; rs < 2; ++rs)
#pragma unroll
        for (int d = 0; d < 4; ++d)
            O[rs][d] = (f32x4){0.f, 0.f, 0.f, 0.f};
    float lsum[2][4] = {{0.f,0.f,0.f,0.f},{0.f,0.f,0.f,0.f}};

    for (int t = 0; t < KEYS_PER_SPLIT; t += 64) {
        const int t0 = tbase + t;
        // staging + mask loads issued before the barrier (latency overlap)
        const size_t gk = (size_t)(t0 + srow) * MD + h * DH + scol;
        const size_t gv = (size_t)(h * DH + srow) * SEQ + t0 + scol;
        const f16x8 k0 = *(const f16x8*)&Kh_g[gk];
        const f16x8 k1 = *(const f16x8*)&Kh_g[gk + 8];
        const f16x8 v0 = *(const f16x8*)&VTh_g[gv];
        const f16x8 v1 = *(const f16x8*)&VTh_g[gv + 8];
        const size_t mb = (((size_t)blockIdx.x * 64 + (size_t)(t0 >> 6)) * 4) * 2048 +
                          (size_t)tid * 8;
        f16x8 bb[4];
#pragma unroll
        for (int c = 0; c < 4; ++c)
            bb[c] = *(const f16x8*)&maskP[mb + (size_t)c * 2048];

        __syncthreads();
        *(f16x8*)&Kh[srow * LDSTR + scol]     = k0;
        *(f16x8*)&Kh[srow * LDSTR + scol + 8] = k1;
        *(f16x8*)&Vh[srow * LDSTR + scol]     = v0;
        *(f16x8*)&Vh[srow * LDSTR + scol + 8] = v1;
        __syncthreads();

        // S = Q @ K^T (2-term: Qh,Ql x Kh), B-frags shared across both rowsets
        f32x4 s[2][4];
#pragma unroll
        for (int rs = 0; rs < 2; ++rs)
#pragma unroll
            for (int st = 0; st < 4; ++st)
                s[rs][st] = (f32x4){0.f, 0.f, 0.f, 0.f};
#pragma unroll
        for (int st = 0; st < 4; ++st)
#pragma unroll
            for (int ks = 0; ks < 2; ++ks) {
                const f16x8 bh = *(f16x8*)&Kh[(st * 16 + ln) * LDSTR + ks * 32 + quad * 8];
#pragma unroll
                for (int rs = 0; rs < 2; ++rs) {
                    s[rs][st] = __builtin_amdgcn_mfma_f32_16x16x32_f16(qh[rs][ks], bh, s[rs][st], 0, 0, 0);
                    s[rs][st] = __builtin_amdgcn_mfma_f32_16x16x32_f16(ql[rs][ks], bh, s[rs][st], 0, 0, 0);
                }
            }

        // softmax numerator (fixed m=0) with permuted bias; P -> LDS
#pragma unroll
        for (int rs = 0; rs < 2; ++rs)
#pragma unroll
            for (int st = 0; st < 4; ++st)
#pragma unroll
                for (int r = 0; r < 4; ++r) {
                    const int c = (rs << 1) + (st >> 1);
                    const int j = ((st & 1) << 2) + r;
                    const float e = exp2f(fmaf(s[rs][st][r], KSC, (float)bb[c][j]));
                    lsum[rs][r] += e;
                    Ph[(wr + rs * 16 + quad * 4 + r) * LDSTR + st * 16 + ln] = (_Float16)e;
                }

        // O += P @ V (1 term); wave-private P rows, no barrier
        f16x8 pa[2][2];
#pragma unroll
        for (int rs = 0; rs < 2; ++rs)
#pragma unroll
            for (int ks = 0; ks < 2; ++ks)
                pa[rs][ks] = *(f16x8*)&Ph[(wr + rs * 16 + ln) * LDSTR + ks * 32 + quad * 8];
#pragma unroll
        for (int dst = 0; dst < 4; ++dst)
#pragma unroll
            for (int ks = 0; ks < 2; ++ks) {
                const f16x8 bh = *(f16x8*)&Vh[(dst * 16 + ln) * LDSTR + ks * 32 + quad * 8];
#pragma unroll
                for (int rs = 0; rs < 2; ++rs)
                    O[rs][dst] = __builtin_amdgcn_mfma_f32_16x16x32_f16(pa[rs][ks], bh,
                                                                        O[rs][dst], 0, 0, 0);
            }
    }

    // l reduction across the 16 lanes sharing each row
#pragma unroll
    for (int rs = 0; rs < 2; ++rs)
#pragma unroll
        for (int r = 0; r < 4; ++r)
#pragma unroll
            for (int off = 8; off >= 1; off >>= 1)
                lsum[rs][r] += __shfl_xor(lsum[rs][r], off);

    // epilogue: store UNNORMALIZED partial O (fp16) + partial l
    _Float16* Op = Opart + (size_t)sp * SEQ * MD;
    float*    lp = lpart + ((size_t)sp * NH + h) * SEQ;
#pragma unroll
    for (int rs = 0; rs < 2; ++rs)
#pragma unroll
        for (int r = 0; r < 4; ++r) {
            const int row = m0 + wr + rs * 16 + quad * 4 + r;
            if (ln == 0) lp[row] = lsum[rs][r];
#pragma unroll
            for (int dst = 0; dst < 4; ++dst)
                Op[(size_t)row * MD + h * DH + dst * 16 + ln] = (_Float16)O[rs][dst][r];
        }
}

// ---------------------------------------------------------------- output GEMM with fused split-combine
__global__ __launch_bounds__(256)
void gemm_out(const _Float16* __restrict__ Opart, const float* __restrict__ lpart,
              const float* __restrict__ Wo, const float* __restrict__ bo,
              float* __restrict__ out)
{
    const size_t NE = (size_t)SEQ * MD;
    __shared__ _Float16 Ash[64 * LDSTR], Asl[64 * LDSTR], Wsh[64 * LDSTR];

    const int tid  = threadIdx.x;
    const int ln   = tid & 15;
    const int quad = (tid & 63) >> 4;
    const int wv_  = tid >> 6;
    const int wr   = wv_ * 16;
    const int m0   = blockIdx.x * 64;
    const int n0   = blockIdx.y * 64;
    const int srow = tid >> 2;
    const int scol = (tid & 3) << 4;

    f32x4 acc[4] = {{0.f,0.f,0.f,0.f},{0.f,0.f,0.f,0.f},
                    {0.f,0.f,0.f,0.f},{0.f,0.f,0.f,0.f}};

    for (int k0 = 0; k0 < MD; k0 += 64) {
        const int row = m0 + srow;
        const int h   = (k0 + scol) >> 6;
        float l = 0.f;
#pragma unroll
        for (int sp = 0; sp < NSPLIT; ++sp)
            l += lpart[((size_t)sp * NH + h) * SEQ + row];
        const float inv = 1.0f / l;

        float cx[16] = {0.f};
#pragma unroll
        for (int sp = 0; sp < NSPLIT; ++sp) {
            const size_t go = (size_t)sp * NE + (size_t)row * MD + k0 + scol;
            const f16x8 o0 = *(const f16x8*)&Opart[go];
            const f16x8 o1 = *(const f16x8*)&Opart[go + 8];
#pragma unroll
            for (int j = 0; j < 8; ++j) { cx[j] += (float)o0[j]; cx[8 + j] += (float)o1[j]; }
        }
        const size_t gw = (size_t)(k0 + srow) * MD + n0 + scol;
        float w[16];
#pragma unroll
        for (int j = 0; j < 4; ++j) {
            const float4 xw = *(const float4*)&Wo[gw + j * 4];
            w[j*4+0] = xw.x; w[j*4+1] = xw.y; w[j*4+2] = xw.z; w[j*4+3] = xw.w;
        }
        f16x8 ah[2], al[2];
#pragma unroll
        for (int half = 0; half < 2; ++half)
#pragma unroll
            for (int j = 0; j < 8; ++j) {
                const float x = cx[half * 8 + j] * inv;
                const _Float16 xh = (_Float16)x;
                ah[half][j] = xh;
                al[half][j] = (_Float16)(x - (float)xh);
            }
        __syncthreads();
        *(f16x8*)&Ash[srow * LDSTR + scol]     = ah[0];
        *(f16x8*)&Ash[srow * LDSTR + scol + 8] = ah[1];
        *(f16x8*)&Asl[srow * LDSTR + scol]     = al[0];
        *(f16x8*)&Asl[srow * LDSTR + scol + 8] = al[1];
#pragma unroll
        for (int j = 0; j < 16; ++j)
            Wsh[(scol + j) * LDSTR + srow] = (_Float16)w[j];
        __syncthreads();

#pragma unroll
        for (int ks = 0; ks < 2; ++ks) {
            const f16x8 fa = *(f16x8*)&Ash[(wr + ln) * LDSTR + ks * 32 + quad * 8];
            const f16x8 fl = *(f16x8*)&Asl[(wr + ln) * LDSTR + ks * 32 + quad * 8];
#pragma unroll
            for (int nt = 0; nt < 4; ++nt) {
                const f16x8 fb = *(f16x8*)&Wsh[(nt * 16 + ln) * LDSTR + ks * 32 + quad * 8];
                acc[nt] = __builtin_amdgcn_mfma_f32_16x16x32_f16(fa, fb, acc[nt], 0, 0, 0);
                acc[nt] = __builtin_amdgcn_mfma_f32_16x16x32_f16(fl, fb, acc[nt], 0, 0, 0);
            }
        }
    }

#pragma unroll
    for (int nt = 0; nt < 4; ++nt) {
        const float bb = bo[n0 + nt * 16 + ln];
#pragma unroll
        for (int r = 0; r < 4; ++r)
            out[(size_t)(m0 + wr + quad * 4 + r) * MD + n0 + nt * 16 + ln] =
                acc[nt][r] + bb;
    }
}

// ---------------------------------------------------------------- launch
extern "C" void kernel_launch(void* const* d_in, const int* in_sizes, int n_in,
                              void* d_out, int out_size, void* d_ws, size_t ws_size,
                              hipStream_t stream)
{
    const float* q    = (const float*)d_in[0];
    const float* k    = (const float*)d_in[1];
    const float* v    = (const float*)d_in[2];
    const float* mask = (const float*)d_in[3];
    const float* wq   = (const float*)d_in[4];
    const float* wk   = (const float*)d_in[5];
    const float* wv   = (const float*)d_in[6];
    const float* wo   = (const float*)d_in[7];
    const float* bo   = (const float*)d_in[8];
    float* out = (float*)d_out;

    const size_t NE = (size_t)SEQ * MD;   // 2M elements
    _Float16* base = (_Float16*)d_ws;
    _Float16* Qh    = base;               // NE
    _Float16* Ql    = base + NE;          // NE
    _Float16* Kh    = base + 2 * NE;      // NE
    _Float16* VTh   = base + 3 * NE;      // NE ([MD][SEQ])
    _Float16* Opart = base + 4 * NE;      // NSPLIT*NE
    _Float16* maskP = base + 6 * NE;      // 8*NE (SEQ*SEQ f16, permuted)
    float*    lpart = (float*)(base + 14 * NE);   // NSPLIT*NH*SEQ fp32

    // 1. projections + mask permute (z=0..2 GEMMs, z=3 mask)
    proj3m<<<dim3(SEQ / 64, MD / 64, 4), 256, 0, stream>>>(q, k, v, mask, wq, wk, wv,
                                                           Qh, Ql, Kh, VTh, maskP);

    // 2. attention, split-K=2 over keys
    attn_mfma<<<dim3(SEQ / 128, NH, NSPLIT), 256, 0, stream>>>(Qh, Ql, Kh, VTh, maskP,
                                                               Opart, lpart);

    // 3. output projection (combine + bias fused)
    gemm_out<<<dim3(SEQ / 64, MD / 64), 256, 0, stream>>>(Opart, lpart, wo, bo, out);
}